// Round 7
// baseline (144.359 us; speedup 1.0000x reference)
//
#include <hip/hip_runtime.h>

// EdgeConv with KNN graph: B=8, N=4096, D=3, E=64, K=32.
// === R23: R21 body (83.5 us verified) + straight-line speculative compact
//          with pk-FREE rare path ===
// R22 post-mortem: retry-loop (backward branch around the 64-slot compact)
// regressed 83.5->91 (VALUBusy 75->63%, scheduler lost the sort->compact
// interleave) AND produced a 31ms outlier dispatch -> structure rejected.
// R23 keeps R22's goal (kill the initial cnt_lt: compaction's running
// `base` IS cnt_lt(H)) with a safe structure:
//  - ONE textual pk-touching compact site, STRAIGHT-LINE on the common
//    path (exactly where R21's compact sat; no backward branch).
//  - rare path (c<32||c>64, sampled-H misses) is PK-FREE: the search
//    counter and pool rebuild RECOMPUTE distances from the LDS planes
//    with the bit-identical fmaf chain -> identical u16 keys -> identical
//    search trajectory and final H as R16/R21. Rebuild iterates t x q ->
//    slot order s=4t+q ascending -> pool byte-identical to R21's compact
//    (incl. pos<64 cap for the H-L<=1 c>64 exit; R6 superset proof).
//  - pk[] live range ENDS at the single compact site -> R17/R19 spill
//    mechanism structurally excluded. Rare loops unroll(disable).
// Predicted: dur 83.5 -> 77-80 us, VALUBusy 71-74%, VGPR 40-48,
// FETCH ~1.7MB, WRITE 8.2MB, occ ~51%, NO outlier dispatches.
// FAIL: VGPR collapse/FETCH>>6MB = spill -> revert R21; any ms-scale
// dispatch -> reject; null 83+/-1 -> pivot to compaction restructure.
// Unchanged: sweep math (BIT-IDENTICAL packed fmaf chain, self-dist == 0),
//  u16 monotone-truncation keys, PER-POINT sampled threshold, DPP lane-XOR
//  (xor1/2/8) bitonics (R21 win: 86.4->83.5), exact-fp32 partial bitonic,
//  lower-index tie-break == jax.lax.top_k, readlane epilogue,
//  2048x16 grid (512,6).
// SPILL DISCIPLINE (R2/R3): every loop touching pk[] FULLY unrolled, ONE
// textual instance of each; 85-VGPR budget. TRIPWIRE: FETCH>6MB.

#define NPTS 4096
#define KNN  32

#define WFENCE() __asm__ volatile("s_waitcnt lgkmcnt(0)" ::: "memory")

typedef unsigned short u16x2 __attribute__((ext_vector_type(2)));
typedef float          f32x2 __attribute__((ext_vector_type(2)));

__device__ __forceinline__ unsigned lane_prefix(unsigned long long m) {
    return __builtin_amdgcn_mbcnt_hi((unsigned)(m >> 32),
           __builtin_amdgcn_mbcnt_lo((unsigned)m, 0u));
}
__device__ __forceinline__ unsigned pk_min_u16(unsigned a, unsigned b) {
    return __builtin_bit_cast(unsigned, __builtin_elementwise_min(
        __builtin_bit_cast(u16x2, a), __builtin_bit_cast(u16x2, b)));
}
// lo16 = top16(d0), hi16 = top16(d1)
__device__ __forceinline__ unsigned pack_keys(float d0, float d1) {
    return __builtin_amdgcn_perm(__builtin_bit_cast(unsigned, d1),
                                 __builtin_bit_cast(unsigned, d0), 0x07060302u);
}
__device__ __forceinline__ unsigned key16(float d) {   // same u16 as pack_keys
    return __builtin_bit_cast(unsigned, d) >> 16;
}

// Lane-XOR exchange. jj in {1,2,8}: DPP on the VALU pipe (quad_perm /
// row_ror:8) -- bit-exact permutation, no DS-pipe use, ~4cy latency.
// jj in {4,16,32}: fall back to __shfl_xor (ds_bpermute).
__device__ __forceinline__ unsigned lane_xor(unsigned v, const int jj) {
    if (jj == 1)
        return (unsigned)__builtin_amdgcn_update_dpp(
            (int)v, (int)v, 0xB1, 0xF, 0xF, false);   // quad_perm [1,0,3,2]
    if (jj == 2)
        return (unsigned)__builtin_amdgcn_update_dpp(
            (int)v, (int)v, 0x4E, 0xF, 0xF, false);   // quad_perm [2,3,0,1]
    if (jj == 8)
        return (unsigned)__builtin_amdgcn_update_dpp(
            (int)v, (int)v, 0x128, 0xF, 0xF, false);  // row_ror:8 == xor8
    return (unsigned)__shfl_xor((int)v, jj, 64);
}

__global__ __launch_bounds__(512, 6)
void edgeconv_knn_kernel(const float* __restrict__ x,
                         const float* __restrict__ theta_w,
                         const float* __restrict__ theta_b,
                         const float* __restrict__ phi_w,
                         const float* __restrict__ phi_b,
                         float* __restrict__ out)
{
    __shared__ float    s_x[NPTS];         // 16 KB per plane (48 KB total)
    __shared__ float    s_y[NPTS];
    __shared__ float    s_z[NPTS];
    __shared__ unsigned s_pool[8][64];     // 2 KB: per-wave survivor indices

    const int tid  = threadIdx.x;
    const int wv   = tid >> 6;
    const int lane = tid & 63;

    const int b  = blockIdx.x >> 8;        // 256 blocks per batch
    const int i0 = (blockIdx.x & 255) << 4;// 16 points per block (2 per wave)

    // lane == output channel e
    const float tw0 = theta_w[lane];
    const float tw1 = theta_w[64 + lane];
    const float tw2 = theta_w[128 + lane];
    const float tbv = theta_b[lane];
    const float pw0 = phi_w[lane];
    const float pw1 = phi_w[64 + lane];
    const float pw2 = phi_w[128 + lane];
    const float pbv = phi_b[lane];

    const float* xb = x + (size_t)b * NPTS * 3;
    for (int p = tid; p < NPTS; p += 512) {
        s_x[p] = xb[p * 3 + 0];
        s_y[p] = xb[p * 3 + 1];
        s_z[p] = xb[p * 3 + 2];
    }
    __syncthreads();

    for (int r = 0; r < 2; ++r) {
        const int i = i0 + wv * 2 + r;
        const float px = s_x[i], py = s_y[i], pz = s_z[i];
        const float sqi = fmaf(pz, pz, fmaf(py, py, px * px));
        const f32x2 PX2 = {px, px}, PY2 = {py, py}, PZ2 = {pz, pz};
        const f32x2 SQI2 = {sqi, sqi};
        const f32x2 N2   = {-2.0f, -2.0f};
        const f32x2 Z02  = {0.0f, 0.0f};

        // distances for slots of sweep-iter t (IDENTICAL chain everywhere)
        auto dist_pair = [&](int t, f32x2& d0, f32x2& d1) {
            const int jb = (t << 8) + (lane << 2);
            const float4 QX = *(const float4*)&s_x[jb];
            const float4 QY = *(const float4*)&s_y[jb];
            const float4 QZ = *(const float4*)&s_z[jb];
            const f32x2 X0 = {QX.x, QX.y}, X1 = {QX.z, QX.w};
            const f32x2 Y0 = {QY.x, QY.y}, Y1 = {QY.z, QY.w};
            const f32x2 Zc0 = {QZ.x, QZ.y}, Zc1 = {QZ.z, QZ.w};
            // sq_j with the identical chain: fma(z,z, fma(y,y, x*x))
            const f32x2 S0 = __builtin_elementwise_fma(Zc0, Zc0,
                             __builtin_elementwise_fma(Y0, Y0, X0 * X0));
            const f32x2 S1 = __builtin_elementwise_fma(Zc1, Zc1,
                             __builtin_elementwise_fma(Y1, Y1, X1 * X1));
            // dot with the identical chain: fma(pz,qz, fma(py,qy, px*qx))
            const f32x2 dt0 = __builtin_elementwise_fma(PZ2, Zc0,
                              __builtin_elementwise_fma(PY2, Y0, PX2 * X0));
            const f32x2 dt1 = __builtin_elementwise_fma(PZ2, Zc1,
                              __builtin_elementwise_fma(PY2, Y1, PX2 * X1));
            d0 = __builtin_elementwise_fma(N2, dt0, SQI2 + S0);
            d1 = __builtin_elementwise_fma(N2, dt1, SQI2 + S1);
            d0 = __builtin_elementwise_max(d0, Z02);
            d1 = __builtin_elementwise_max(d1, Z02);
        };

        // ---- sweep: lane owns candidates j = 256*t + 4*lane + {0..3} ----
        // slot s=0..63 -> j = ((s>>2)<<8) + (lane<<2) + (s&3)
        unsigned pk[32];
        unsigned pmin = 0xFFFFFFFFu;
        #pragma unroll
        for (int t = 0; t < 16; ++t) {
            f32x2 d0, d1;
            dist_pair(t, d0, d1);
            pk[2 * t]     = pack_keys(d0.x, d0.y);
            pk[2 * t + 1] = pack_keys(d1.x, d1.y);
            pmin = pk_min_u16(pmin, pk[2 * t]);
            pmin = pk_min_u16(pmin, pk[2 * t + 1]);
        }
        unsigned mn = min(pmin & 0xFFFFu, pmin >> 16);   // per-lane min (u16)

        // ---- PER-POINT bitonic sort of 64 lane-minima -> sampled threshold
        #pragma unroll
        for (int k = 2; k <= 64; k <<= 1) {
            #pragma unroll
            for (int jj = k >> 1; jj >= 1; jj >>= 1) {
                const unsigned o = lane_xor(mn, jj);
                const bool wantmin = (((lane & k) == 0) == ((lane & jj) == 0));
                const bool less = (mn < o);
                if (less != wantmin) mn = o;
            }
        }
        unsigned H = (unsigned)__builtin_amdgcn_readlane((int)mn, 32);

        // ---- SPECULATIVE compaction with sampled H (ONE pk site, straight
        // line). base == cnt_lt(H) exactly (popc over all 64 ballots). ----
        WFENCE();                            // prior pool consumers done
        unsigned base = 0;
        #pragma unroll
        for (int s = 0; s < 64; ++s) {
            const unsigned kk = (s & 1) ? (pk[s >> 1] >> 16)
                                        : (pk[s >> 1] & 0xFFFFu);
            const bool pred = kk < H;
            const unsigned long long bm = __ballot(pred);
            if (bm) {
                if (pred) {
                    const unsigned pos = base + lane_prefix(bm);
                    if (pos < 64u)
                        s_pool[wv][pos] =
                            (unsigned)(((s >> 2) << 8) + (lane << 2) + (s & 3));
                }
                base += (unsigned)__popcll(bm);
            }
        }
        WFENCE();
        unsigned c = base;                   // pk[] DEAD from here on

        // ---- rare path: sampled H missed [32,64]. PK-FREE: recompute keys
        // from LDS (identical chain -> identical u16 keys -> identical
        // search trajectory as R16/R21), then rebuild pool in slot order.
        if (__builtin_expect(c < KNN || c > 64u, 0)) {
            auto cnt_rec = [&](unsigned T) -> unsigned {
                unsigned cc = 0;
                #pragma clang loop unroll(disable)
                for (int t = 0; t < 16; ++t) {
                    f32x2 d0, d1;
                    dist_pair(t, d0, d1);
                    cc += (unsigned)__popcll(__ballot(key16(d0.x) < T));
                    cc += (unsigned)__popcll(__ballot(key16(d0.y) < T));
                    cc += (unsigned)__popcll(__ballot(key16(d1.x) < T));
                    cc += (unsigned)__popcll(__ballot(key16(d1.y) < T));
                }
                return cc;
            };
            unsigned Lb = 0u;
            if (c < KNN) {                   // raise by octaves (exp LSB 0x80)
                unsigned step = 0x80u;
                do {
                    unsigned Hn = H + step;
                    if (Hn > 0xFFFFu) Hn = 0xFFFFu;
                    Lb = H; H = Hn; step <<= 1;
                    c = cnt_rec(H);
                } while (c < KNN);
            }
            while (c > 64u && (H - Lb) > 1u) {
                const unsigned M  = Lb + ((H - Lb) >> 1);
                const unsigned cm = cnt_rec(M);
                if (cm >= KNN) { H = M; c = cm; } else { Lb = M; }
            }
            // rebuild pool with final H; slot order s = 4t+q ascending ->
            // byte-identical to the compact loop's pool (incl. pos<64 cap).
            WFENCE();
            base = 0;
            #pragma clang loop unroll(disable)
            for (int t = 0; t < 16; ++t) {
                f32x2 d0, d1;
                dist_pair(t, d0, d1);
                unsigned kq[4];
                kq[0] = key16(d0.x); kq[1] = key16(d0.y);
                kq[2] = key16(d1.x); kq[3] = key16(d1.y);
                #pragma unroll
                for (int q = 0; q < 4; ++q) {
                    const bool pred = kq[q] < H;
                    const unsigned long long bm = __ballot(pred);
                    if (bm) {
                        if (pred) {
                            const unsigned pos = base + lane_prefix(bm);
                            if (pos < 64u)
                                s_pool[wv][pos] =
                                    (unsigned)((t << 8) + (lane << 2) + q);
                        }
                        base += (unsigned)__popcll(bm);
                    }
                }
            }
            WFENCE();
            c = base;
        }
        const unsigned m = c < 64u ? c : 64u;   // m >= 32 guaranteed

        // ---- exact fp32 keys for pool members (identical op chain) ----
        unsigned myk = 0xFFFFFFFFu;
        unsigned myj = 0u;                   // sentinel, never selected (m>=32)
        if ((unsigned)lane < m) {
            myj = s_pool[wv][lane];
            const float qx = s_x[myj], qy = s_y[myj], qz = s_z[myj];
            const float sqj = fmaf(qz, qz, fmaf(qy, qy, qx * qx));
            const float dt  = fmaf(pz, qz, fmaf(py, qy, px * qx));
            float d = fmaf(-2.0f, dt, sqi + sqj);
            d = fmaxf(d, 0.0f);
            myk = __builtin_bit_cast(unsigned, d);
        }

        // ---- partial bitonic: 32-sorts + one merge -> bottom-32 unordered ----
        #pragma unroll
        for (int k = 2; k <= 32; k <<= 1) {
            #pragma unroll
            for (int jj = k >> 1; jj >= 1; jj >>= 1) {
                const unsigned ok = lane_xor(myk, jj);
                const unsigned oj = lane_xor(myj, jj);
                const bool wantmin = (((lane & k) == 0) == ((lane & jj) == 0));
                const bool less = (myk < ok) || (myk == ok && myj < oj);
                if (less != wantmin) { myk = ok; myj = oj; }
            }
        }
        {   // k=64, jj=32: lanes 0..31 <- the 32 smallest (unordered)
            const unsigned ok = (unsigned)__shfl_xor((int)myk, 32, 64);
            const unsigned oj = (unsigned)__shfl_xor((int)myj, 32, 64);
            const bool wantmin = ((lane & 32) == 0);
            const bool less = (myk < ok) || (myk == ok && myj < oj);
            if (less != wantmin) { myk = ok; myj = oj; }
        }

        // ---- epilogue: lane = channel e; max over the 32 selected ----
        float dx = 0.f, dy = 0.f, dz = 0.f;
        if (lane < KNN) {
            dx = s_x[myj] - px; dy = s_y[myj] - py; dz = s_z[myj] - pz;
        }
        const float basev = tbv + pbv + fmaf(pw2, pz, fmaf(pw1, py, pw0 * px));
        float mx = -3.0e38f;
        #pragma unroll
        for (int t = 0; t < KNN; ++t) {
            const float ndx = __builtin_bit_cast(float, __builtin_amdgcn_readlane(__builtin_bit_cast(int, dx), t));
            const float ndy = __builtin_bit_cast(float, __builtin_amdgcn_readlane(__builtin_bit_cast(int, dy), t));
            const float ndz = __builtin_bit_cast(float, __builtin_amdgcn_readlane(__builtin_bit_cast(int, dz), t));
            const float proj = fmaf(tw2, ndz, fmaf(tw1, ndy, tw0 * ndx));
            mx = fmaxf(mx, proj);
        }
        out[(((size_t)b * NPTS + (size_t)i) << 6) + lane] = mx + basev;
    }
}

extern "C" void kernel_launch(void* const* d_in, const int* in_sizes, int n_in,
                              void* d_out, int out_size, void* d_ws, size_t ws_size,
                              hipStream_t stream) {
    const float* x  = (const float*)d_in[0];
    const float* tw = (const float*)d_in[1];
    const float* tb = (const float*)d_in[2];
    const float* pw = (const float*)d_in[3];
    const float* pb = (const float*)d_in[4];
    float* out = (float*)d_out;

    dim3 grid(8 * 256);   // 2048 blocks x 16 pts (R16 verified geometry)
    dim3 block(512);
    hipLaunchKernelGGL(edgeconv_knn_kernel, grid, block, 0, stream,
                       x, tw, tb, pw, pb, out);
}

// Round 8
// 133.701 us; speedup vs baseline: 1.0797x; 1.0797x over previous
//
#include <hip/hip_runtime.h>

// EdgeConv with KNN graph: B=8, N=4096, D=3, E=64, K=32.
// === R24: R21 body/structure FROZEN (83.5 us verified) + extract-free
//          u16 predicates in cnt_lt and compact (bit-exact, no asm) ===
// R22/R23 post-mortem: BOTH speculative-compact variants regressed (91/94
// us, VALUBusy 75->63%, occ ->41%) with clean VGPR/FETCH -> the structure
// perturbation, not spill, is the cost. Idea abandoned; R21 structure
// (cnt_lt -> search(rare) -> ONE compact) is FROZEN.
// R24 mechanism: every u16 key test paid extract+cmp (2 VALU). Replaced by
// single compares with PROVEN-identical predicates:
//   hi:  (pk>>16) < T  <=>  pk < (T<<16)   [u32; T<=0xFFFF always: sampled
//        H is a u16 key, octave raise clamps at 0xFFFF, bisect M < H]
//   lo:  (pk & 0xFFFF) < T  <=>  (u16)pk < (u16)T   [v_cmp_lt_u16 reads
//        low half natively, no v_and]
// Applied at cnt_lt (64 keys) + compact (64 slots): ~128 VALU instr/point
// removed (~16% of the 1566-cyc point budget). Selection bit-identical.
// Predicted: dur 83.5 -> 74-78 us, VALUBusy 71-75%, VGPR ~40, FETCH
// ~1.7MB, WRITE 8.2MB, occ ~51%, no outliers.
// FAIL READ: null (83+/-1) => clang already emitted u16 cmps -> next lever
// is asm-packed epilogue; FETCH spike => spill -> revert R21 verbatim.
// Unchanged: sweep math (BIT-IDENTICAL packed fmaf chain, self-dist == 0),
//  u16 monotone-truncation keys, PER-POINT sampled threshold, DPP lane-XOR
//  (xor1/2/8) bitonics (R21 win), octave/bisect search, ONE index-only
//  compaction (slot order + pos<64 cap, R6 superset proof), exact-fp32
//  partial bitonic, lower-index tie-break == jax.lax.top_k, readlane
//  epilogue, 2048x16 grid (512,6).
// SPILL DISCIPLINE (R2/R3): every loop touching pk[] FULLY unrolled, ONE
// textual instance of each; 85-VGPR budget. TRIPWIRE: FETCH>6MB.

#define NPTS 4096
#define KNN  32

#define WFENCE() __asm__ volatile("s_waitcnt lgkmcnt(0)" ::: "memory")

typedef unsigned short u16x2 __attribute__((ext_vector_type(2)));
typedef float          f32x2 __attribute__((ext_vector_type(2)));

__device__ __forceinline__ unsigned lane_prefix(unsigned long long m) {
    return __builtin_amdgcn_mbcnt_hi((unsigned)(m >> 32),
           __builtin_amdgcn_mbcnt_lo((unsigned)m, 0u));
}
__device__ __forceinline__ unsigned pk_min_u16(unsigned a, unsigned b) {
    return __builtin_bit_cast(unsigned, __builtin_elementwise_min(
        __builtin_bit_cast(u16x2, a), __builtin_bit_cast(u16x2, b)));
}
// lo16 = top16(d0), hi16 = top16(d1)
__device__ __forceinline__ unsigned pack_keys(float d0, float d1) {
    return __builtin_amdgcn_perm(__builtin_bit_cast(unsigned, d1),
                                 __builtin_bit_cast(unsigned, d0), 0x07060302u);
}

// Lane-XOR exchange. jj in {1,2,8}: DPP on the VALU pipe (quad_perm /
// row_ror:8) -- bit-exact permutation, no DS-pipe use, ~4cy latency.
// jj in {4,16,32}: fall back to __shfl_xor (ds_bpermute).
__device__ __forceinline__ unsigned lane_xor(unsigned v, const int jj) {
    if (jj == 1)
        return (unsigned)__builtin_amdgcn_update_dpp(
            (int)v, (int)v, 0xB1, 0xF, 0xF, false);   // quad_perm [1,0,3,2]
    if (jj == 2)
        return (unsigned)__builtin_amdgcn_update_dpp(
            (int)v, (int)v, 0x4E, 0xF, 0xF, false);   // quad_perm [2,3,0,1]
    if (jj == 8)
        return (unsigned)__builtin_amdgcn_update_dpp(
            (int)v, (int)v, 0x128, 0xF, 0xF, false);  // row_ror:8 == xor8
    return (unsigned)__shfl_xor((int)v, jj, 64);
}

__global__ __launch_bounds__(512, 6)
void edgeconv_knn_kernel(const float* __restrict__ x,
                         const float* __restrict__ theta_w,
                         const float* __restrict__ theta_b,
                         const float* __restrict__ phi_w,
                         const float* __restrict__ phi_b,
                         float* __restrict__ out)
{
    __shared__ float    s_x[NPTS];         // 16 KB per plane (48 KB total)
    __shared__ float    s_y[NPTS];
    __shared__ float    s_z[NPTS];
    __shared__ unsigned s_pool[8][64];     // 2 KB: per-wave survivor indices

    const int tid  = threadIdx.x;
    const int wv   = tid >> 6;
    const int lane = tid & 63;

    const int b  = blockIdx.x >> 8;        // 256 blocks per batch
    const int i0 = (blockIdx.x & 255) << 4;// 16 points per block (2 per wave)

    // lane == output channel e
    const float tw0 = theta_w[lane];
    const float tw1 = theta_w[64 + lane];
    const float tw2 = theta_w[128 + lane];
    const float tbv = theta_b[lane];
    const float pw0 = phi_w[lane];
    const float pw1 = phi_w[64 + lane];
    const float pw2 = phi_w[128 + lane];
    const float pbv = phi_b[lane];

    const float* xb = x + (size_t)b * NPTS * 3;
    for (int p = tid; p < NPTS; p += 512) {
        s_x[p] = xb[p * 3 + 0];
        s_y[p] = xb[p * 3 + 1];
        s_z[p] = xb[p * 3 + 2];
    }
    __syncthreads();

    for (int r = 0; r < 2; ++r) {
        const int i = i0 + wv * 2 + r;
        const float px = s_x[i], py = s_y[i], pz = s_z[i];
        const float sqi = fmaf(pz, pz, fmaf(py, py, px * px));
        const f32x2 PX2 = {px, px}, PY2 = {py, py}, PZ2 = {pz, pz};
        const f32x2 SQI2 = {sqi, sqi};
        const f32x2 N2   = {-2.0f, -2.0f};
        const f32x2 Z02  = {0.0f, 0.0f};

        // ---- sweep: lane owns candidates j = 256*t + 4*lane + {0..3} ----
        // slot s=0..63 -> j = ((s>>2)<<8) + (lane<<2) + (s&3)
        unsigned pk[32];
        unsigned pmin = 0xFFFFFFFFu;
        #pragma unroll
        for (int t = 0; t < 16; ++t) {
            const int jb = (t << 8) + (lane << 2);
            const float4 QX = *(const float4*)&s_x[jb];
            const float4 QY = *(const float4*)&s_y[jb];
            const float4 QZ = *(const float4*)&s_z[jb];
            const f32x2 X0 = {QX.x, QX.y}, X1 = {QX.z, QX.w};
            const f32x2 Y0 = {QY.x, QY.y}, Y1 = {QY.z, QY.w};
            const f32x2 Zc0 = {QZ.x, QZ.y}, Zc1 = {QZ.z, QZ.w};
            // sq_j with the identical chain: fma(z,z, fma(y,y, x*x))
            const f32x2 S0 = __builtin_elementwise_fma(Zc0, Zc0,
                             __builtin_elementwise_fma(Y0, Y0, X0 * X0));
            const f32x2 S1 = __builtin_elementwise_fma(Zc1, Zc1,
                             __builtin_elementwise_fma(Y1, Y1, X1 * X1));
            // dot with the identical chain: fma(pz,qz, fma(py,qy, px*qx))
            const f32x2 dt0 = __builtin_elementwise_fma(PZ2, Zc0,
                              __builtin_elementwise_fma(PY2, Y0, PX2 * X0));
            const f32x2 dt1 = __builtin_elementwise_fma(PZ2, Zc1,
                              __builtin_elementwise_fma(PY2, Y1, PX2 * X1));
            f32x2 d0 = __builtin_elementwise_fma(N2, dt0, SQI2 + S0);
            f32x2 d1 = __builtin_elementwise_fma(N2, dt1, SQI2 + S1);
            d0 = __builtin_elementwise_max(d0, Z02);
            d1 = __builtin_elementwise_max(d1, Z02);
            pk[2 * t]     = pack_keys(d0.x, d0.y);
            pk[2 * t + 1] = pack_keys(d1.x, d1.y);
            pmin = pk_min_u16(pmin, pk[2 * t]);
            pmin = pk_min_u16(pmin, pk[2 * t + 1]);
        }
        unsigned mn = min(pmin & 0xFFFFu, pmin >> 16);   // per-lane min (u16)

        // ---- PER-POINT bitonic sort of 64 lane-minima -> sampled threshold
        #pragma unroll
        for (int k = 2; k <= 64; k <<= 1) {
            #pragma unroll
            for (int jj = k >> 1; jj >= 1; jj >>= 1) {
                const unsigned o = lane_xor(mn, jj);
                const bool wantmin = (((lane & k) == 0) == ((lane & jj) == 0));
                const bool less = (mn < o);
                if (less != wantmin) mn = o;
            }
        }
        unsigned H = (unsigned)__builtin_amdgcn_readlane((int)mn, 32);

        // wave-uniform count of u16 keys strictly below T (ballot -> scalar).
        // Extract-free predicates (bit-exact):
        //   lo: (u16)pk < (u16)T        (v_cmp_lt_u16 reads low half)
        //   hi: pk < (T<<16)  <=>  (pk>>16) < T   (T <= 0xFFFF always)
        auto cnt_lt = [&](unsigned T) -> unsigned {
            const unsigned Thi = T << 16;
            unsigned c2 = 0;
            #pragma unroll
            for (int k2 = 0; k2 < 32; ++k2) {
                c2 += (unsigned)__popcll(__ballot(
                        (unsigned short)pk[k2] < (unsigned short)T));
                c2 += (unsigned)__popcll(__ballot(pk[k2] < Thi));
            }
            return c2;
        };

        // ---- threshold search in u16 key space ----
        unsigned L = 0u;
        unsigned c = cnt_lt(H);
        if (c < KNN) {                       // raise by octaves (exp LSB = 0x80)
            unsigned step = 0x80u;
            do {
                unsigned Hn = H + step;
                if (Hn > 0xFFFFu) Hn = 0xFFFFu;
                L = H; H = Hn; step <<= 1;
                c = cnt_lt(H);
            } while (c < KNN);
        }
        while (c > 64u && (H - L) > 1u) {
            const unsigned M  = L + ((H - L) >> 1);
            const unsigned cm = cnt_lt(M);
            if (cm >= KNN) { H = M; c = cm; } else { L = M; }
        }

        // ---- compaction: survivor indices only (ballot + mbcnt) ----
        // Same extract-free predicates; slot order and pos<64 cap unchanged.
        WFENCE();                            // prior pool consumers done
        const unsigned Hhi = H << 16;
        unsigned base = 0;
        #pragma unroll
        for (int s = 0; s < 64; ++s) {
            const bool pred = (s & 1)
                ? (pk[s >> 1] < Hhi)
                : ((unsigned short)pk[s >> 1] < (unsigned short)H);
            const unsigned long long bm = __ballot(pred);
            if (bm) {
                if (pred) {
                    const unsigned pos = base + lane_prefix(bm);
                    if (pos < 64u)
                        s_pool[wv][pos] =
                            (unsigned)(((s >> 2) << 8) + (lane << 2) + (s & 3));
                }
                base += (unsigned)__popcll(bm);
            }
        }
        WFENCE();
        const unsigned m = base < 64u ? base : 64u;   // m >= 32 guaranteed

        // ---- exact fp32 keys for pool members (identical op chain) ----
        unsigned myk = 0xFFFFFFFFu;
        unsigned myj = 0u;                   // sentinel, never selected (m>=32)
        if ((unsigned)lane < m) {
            myj = s_pool[wv][lane];
            const float qx = s_x[myj], qy = s_y[myj], qz = s_z[myj];
            const float sqj = fmaf(qz, qz, fmaf(qy, qy, qx * qx));
            const float dt  = fmaf(pz, qz, fmaf(py, qy, px * qx));
            float d = fmaf(-2.0f, dt, sqi + sqj);
            d = fmaxf(d, 0.0f);
            myk = __builtin_bit_cast(unsigned, d);
        }

        // ---- partial bitonic: 32-sorts + one merge -> bottom-32 unordered ----
        #pragma unroll
        for (int k = 2; k <= 32; k <<= 1) {
            #pragma unroll
            for (int jj = k >> 1; jj >= 1; jj >>= 1) {
                const unsigned ok = lane_xor(myk, jj);
                const unsigned oj = lane_xor(myj, jj);
                const bool wantmin = (((lane & k) == 0) == ((lane & jj) == 0));
                const bool less = (myk < ok) || (myk == ok && myj < oj);
                if (less != wantmin) { myk = ok; myj = oj; }
            }
        }
        {   // k=64, jj=32: lanes 0..31 <- the 32 smallest (unordered)
            const unsigned ok = (unsigned)__shfl_xor((int)myk, 32, 64);
            const unsigned oj = (unsigned)__shfl_xor((int)myj, 32, 64);
            const bool wantmin = ((lane & 32) == 0);
            const bool less = (myk < ok) || (myk == ok && myj < oj);
            if (less != wantmin) { myk = ok; myj = oj; }
        }

        // ---- epilogue: lane = channel e; max over the 32 selected ----
        float dx = 0.f, dy = 0.f, dz = 0.f;
        if (lane < KNN) {
            dx = s_x[myj] - px; dy = s_y[myj] - py; dz = s_z[myj] - pz;
        }
        const float basev = tbv + pbv + fmaf(pw2, pz, fmaf(pw1, py, pw0 * px));
        float mx = -3.0e38f;
        #pragma unroll
        for (int t = 0; t < KNN; ++t) {
            const float ndx = __builtin_bit_cast(float, __builtin_amdgcn_readlane(__builtin_bit_cast(int, dx), t));
            const float ndy = __builtin_bit_cast(float, __builtin_amdgcn_readlane(__builtin_bit_cast(int, dy), t));
            const float ndz = __builtin_bit_cast(float, __builtin_amdgcn_readlane(__builtin_bit_cast(int, dz), t));
            const float proj = fmaf(tw2, ndz, fmaf(tw1, ndy, tw0 * ndx));
            mx = fmaxf(mx, proj);
        }
        out[(((size_t)b * NPTS + (size_t)i) << 6) + lane] = mx + basev;
    }
}

extern "C" void kernel_launch(void* const* d_in, const int* in_sizes, int n_in,
                              void* d_out, int out_size, void* d_ws, size_t ws_size,
                              hipStream_t stream) {
    const float* x  = (const float*)d_in[0];
    const float* tw = (const float*)d_in[1];
    const float* tb = (const float*)d_in[2];
    const float* pw = (const float*)d_in[3];
    const float* pb = (const float*)d_in[4];
    float* out = (float*)d_out;

    dim3 grid(8 * 256);   // 2048 blocks x 16 pts (R16 verified geometry)
    dim3 block(512);
    hipLaunchKernelGGL(edgeconv_knn_kernel, grid, block, 0, stream,
                       x, tw, tb, pw, pb, out);
}